// Round 1
// baseline (1347.822 us; speedup 1.0000x reference)
//
#include <hip/hip_runtime.h>
#include <hip/hip_bf16.h>
#include <math.h>

#define BATCH 2048
#define INDIM 512
#define HID   256
#define NRIM  16
#define VAL   400
#define ONUM  8
#define CH    4
#define CK    32
#define CV    256
#define KACT  8

typedef __hip_bfloat16 bf16;

__device__ __forceinline__ float sigmoidf_(float x) { return 1.0f / (1.0f + expf(-x)); }

// K1: scores, top-k mask, softmax p0, value_layer row0 (vl0 = x @ value_w + b)
__global__ __launch_bounds__(256)
void k1_prep(const float* __restrict__ x, const float* __restrict__ option,
             const float* __restrict__ value_w, const float* __restrict__ value_b,
             const float* __restrict__ p_w, const float* __restrict__ p_b,
             float* __restrict__ vl0, float* __restrict__ p0g, float* __restrict__ maskg)
{
    const int b = blockIdx.x;
    const int t = threadIdx.x;
    __shared__ float xS[INDIM];
    __shared__ float sc[NRIM][2];

    xS[t]       = x[b * INDIM + t];
    xS[t + 256] = x[b * INDIM + t + 256];

    if (t < 32) {
        int n = t & 15, i = t >> 4;
        float s = (i == 0) ? p_b[n] : 0.0f;
        #pragma unroll
        for (int o = 0; o < ONUM; ++o)
            s = fmaf(option[(b * 2 + i) * ONUM + o], p_w[o * NRIM + n], s);
        sc[n][i] = s;
    }
    __syncthreads();

    if (t < NRIM) {
        int n = t;
        float s0 = sc[n][0], s1 = sc[n][1];
        int rank = 0;
        for (int m = 0; m < NRIM; ++m) {
            float sm = sc[m][0];
            if (sm > s0 || (sm == s0 && m < n)) rank++;
        }
        float mk = (rank < KACT) ? 1.0f : 0.0f;
        float mx = fmaxf(s0, s1);
        float e0 = expf(s0 - mx), e1 = expf(s1 - mx);
        p0g[b * NRIM + n]   = e0 / (e0 + e1);
        maskg[b * NRIM + n] = mk;
    }

    // vl0[b][c] = sum_i x[b][i] * value_w[i][c] + value_b[c]
    for (int c = t; c < VAL; c += 256) {
        float acc = value_b[c];
        for (int i = 0; i < INDIM; ++i)
            acc = fmaf(xS[i], value_w[i * VAL + c], acc);
        vl0[b * VAL + c] = acc;
    }
}

// K2: GRU per (n, batch-tile of 16). gh = hs@h2h_w[n], gx = inputs@x2h_w[n]
__global__ __launch_bounds__(256)
void k2_gru(const float* __restrict__ hs, const float* __restrict__ vl0,
            const float* __restrict__ p0g, const float* __restrict__ maskg,
            const float* __restrict__ value_b,
            const float* __restrict__ x2h_w, const float* __restrict__ h2h_w,
            float* __restrict__ hy)
{
    const int n  = blockIdx.x;
    const int b0 = blockIdx.y * 16;
    const int t  = threadIdx.x;   // output column h in [0,256)

    __shared__ float hsS[HID][20];   // transposed: hsS[d][bb]
    __shared__ float inS[VAL][20];   // transposed: inS[j][bb]
    __shared__ float p0S[16], mS[16];

    if (t < 16) {
        p0S[t] = p0g[(b0 + t) * NRIM + n];
        mS[t]  = maskg[(b0 + t) * NRIM + n];
    }
    __syncthreads();

    for (int i = 0; i < 16; ++i)
        hsS[t][i] = hs[((b0 + i) * NRIM + n) * HID + t];

    for (int i = 0; i < 16; ++i) {
        float p0 = p0S[i], mk = mS[i];
        for (int j = t; j < VAL; j += 256) {
            float v = p0 * vl0[(b0 + i) * VAL + j] + (1.0f - p0) * value_b[j];
            inS[j][i] = mk * v;
        }
    }
    __syncthreads();

    float accR[16], accI[16], ghN[16], gxN[16];
    #pragma unroll
    for (int i = 0; i < 16; ++i) { accR[i] = 0.f; accI[i] = 0.f; ghN[i] = 0.f; gxN[i] = 0.f; }

    const float* h2h = h2h_w + (size_t)n * HID * 768;
    for (int d = 0; d < HID; ++d) {
        float wr = h2h[d * 768 + t];
        float wi = h2h[d * 768 + t + 256];
        float wn = h2h[d * 768 + t + 512];
        const float4* hrow = (const float4*)(&hsS[d][0]);
        #pragma unroll
        for (int g = 0; g < 4; ++g) {
            float4 h4 = hrow[g];
            accR[4*g+0] = fmaf(h4.x, wr, accR[4*g+0]);
            accR[4*g+1] = fmaf(h4.y, wr, accR[4*g+1]);
            accR[4*g+2] = fmaf(h4.z, wr, accR[4*g+2]);
            accR[4*g+3] = fmaf(h4.w, wr, accR[4*g+3]);
            accI[4*g+0] = fmaf(h4.x, wi, accI[4*g+0]);
            accI[4*g+1] = fmaf(h4.y, wi, accI[4*g+1]);
            accI[4*g+2] = fmaf(h4.z, wi, accI[4*g+2]);
            accI[4*g+3] = fmaf(h4.w, wi, accI[4*g+3]);
            ghN[4*g+0]  = fmaf(h4.x, wn, ghN[4*g+0]);
            ghN[4*g+1]  = fmaf(h4.y, wn, ghN[4*g+1]);
            ghN[4*g+2]  = fmaf(h4.z, wn, ghN[4*g+2]);
            ghN[4*g+3]  = fmaf(h4.w, wn, ghN[4*g+3]);
        }
    }

    const float* x2h = x2h_w + (size_t)n * VAL * 768;
    for (int j = 0; j < VAL; ++j) {
        float wr = x2h[j * 768 + t];
        float wi = x2h[j * 768 + t + 256];
        float wn = x2h[j * 768 + t + 512];
        const float4* irow = (const float4*)(&inS[j][0]);
        #pragma unroll
        for (int g = 0; g < 4; ++g) {
            float4 h4 = irow[g];
            accR[4*g+0] = fmaf(h4.x, wr, accR[4*g+0]);
            accR[4*g+1] = fmaf(h4.y, wr, accR[4*g+1]);
            accR[4*g+2] = fmaf(h4.z, wr, accR[4*g+2]);
            accR[4*g+3] = fmaf(h4.w, wr, accR[4*g+3]);
            accI[4*g+0] = fmaf(h4.x, wi, accI[4*g+0]);
            accI[4*g+1] = fmaf(h4.y, wi, accI[4*g+1]);
            accI[4*g+2] = fmaf(h4.z, wi, accI[4*g+2]);
            accI[4*g+3] = fmaf(h4.w, wi, accI[4*g+3]);
            gxN[4*g+0]  = fmaf(h4.x, wn, gxN[4*g+0]);
            gxN[4*g+1]  = fmaf(h4.y, wn, gxN[4*g+1]);
            gxN[4*g+2]  = fmaf(h4.z, wn, gxN[4*g+2]);
            gxN[4*g+3]  = fmaf(h4.w, wn, gxN[4*g+3]);
        }
    }

    #pragma unroll
    for (int i = 0; i < 16; ++i) {
        float reset = sigmoidf_(accR[i]);
        float inp   = sigmoidf_(accI[i]);
        float newg  = tanhf(gxN[i] + reset * ghN[i]);
        float hv    = hsS[t][i];
        hy[((b0 + i) * NRIM + n) * HID + t] = newg + inp * (hv - newg);
    }
}

// K3: q,k,v projections per (ctile, n, batch-tile). col-space: [q 128 | k 128 | v 1024]
__global__ __launch_bounds__(256)
void k3_qkv(const float* __restrict__ hy,
            const float* __restrict__ q_w, const float* __restrict__ k_w,
            const float* __restrict__ v_w,
            float* __restrict__ qo, float* __restrict__ ko, bf16* __restrict__ vo)
{
    const int ctile = blockIdx.x;  // 0..4
    const int n     = blockIdx.y;
    const int b0    = blockIdx.z * 16;
    const int t     = threadIdx.x;

    __shared__ float hyS[HID][20];
    for (int i = 0; i < 16; ++i)
        hyS[t][i] = hy[((b0 + i) * NRIM + n) * HID + t];
    __syncthreads();

    const int col = ctile * 256 + t;
    const float* wbase;
    int wstride;
    if (col < 128)      { wbase = q_w + (size_t)n * HID * 128 + col;          wstride = 128;  }
    else if (col < 256) { wbase = k_w + (size_t)n * HID * 128 + (col - 128);  wstride = 128;  }
    else                { wbase = v_w + (size_t)n * HID * 1024 + (col - 256); wstride = 1024; }

    float acc[16];
    #pragma unroll
    for (int i = 0; i < 16; ++i) acc[i] = 0.f;

    for (int d = 0; d < HID; ++d) {
        float w = wbase[(size_t)d * wstride];
        const float4* hrow = (const float4*)(&hyS[d][0]);
        #pragma unroll
        for (int g = 0; g < 4; ++g) {
            float4 h4 = hrow[g];
            acc[4*g+0] = fmaf(h4.x, w, acc[4*g+0]);
            acc[4*g+1] = fmaf(h4.y, w, acc[4*g+1]);
            acc[4*g+2] = fmaf(h4.z, w, acc[4*g+2]);
            acc[4*g+3] = fmaf(h4.w, w, acc[4*g+3]);
        }
    }

    if (col < 128) {
        #pragma unroll
        for (int i = 0; i < 16; ++i)
            qo[((b0 + i) * NRIM + n) * 128 + col] = acc[i];
    } else if (col < 256) {
        #pragma unroll
        for (int i = 0; i < 16; ++i)
            ko[((b0 + i) * NRIM + n) * 128 + (col - 128)] = acc[i];
    } else {
        #pragma unroll
        for (int i = 0; i < 16; ++i)
            vo[((b0 + i) * NRIM + n) * 1024 + (col - 256)] = __float2bfloat16(acc[i]);
    }
}

// K4: attention per (h, b): 16x16 scores, softmax, row-mask, ctx = att @ v
__global__ __launch_bounds__(256)
void k4_attn(const float* __restrict__ qo, const float* __restrict__ ko,
             const bf16* __restrict__ vo, const float* __restrict__ maskg,
             bf16* __restrict__ ctx)
{
    const int h = blockIdx.x;
    const int b = blockIdx.y;
    const int t = threadIdx.x;

    __shared__ float qS[NRIM][33], kS[NRIM][33];
    __shared__ float sS[NRIM][17];
    __shared__ float vS[NRIM][CV];
    __shared__ float mS[NRIM];

    for (int idx = t; idx < NRIM * CK; idx += 256) {
        int n2 = idx >> 5, i = idx & 31;
        qS[n2][i] = qo[(b * NRIM + n2) * 128 + h * CK + i];
        kS[n2][i] = ko[(b * NRIM + n2) * 128 + h * CK + i];
    }
    for (int idx = t; idx < NRIM * CV; idx += 256) {
        int m2 = idx >> 8, c = idx & 255;
        vS[m2][c] = __bfloat162float(vo[(b * NRIM + m2) * 1024 + h * CV + c]);
    }
    if (t < NRIM) mS[t] = maskg[b * NRIM + t];
    __syncthreads();

    {
        int nn = t >> 4, mm = t & 15;
        float s = 0.f;
        #pragma unroll
        for (int i = 0; i < CK; ++i) s = fmaf(qS[nn][i], kS[mm][i], s);
        sS[nn][mm] = s * 0.17677669529663687f;  // 1/sqrt(32)
    }
    __syncthreads();

    if (t < NRIM) {
        float mx = -1e30f;
        #pragma unroll
        for (int m2 = 0; m2 < NRIM; ++m2) mx = fmaxf(mx, sS[t][m2]);
        float sum = 0.f;
        #pragma unroll
        for (int m2 = 0; m2 < NRIM; ++m2) { float e = expf(sS[t][m2] - mx); sS[t][m2] = e; sum += e; }
        float inv = mS[t] / sum;
        #pragma unroll
        for (int m2 = 0; m2 < NRIM; ++m2) sS[t][m2] *= inv;
    }
    __syncthreads();

    for (int n2 = 0; n2 < NRIM; ++n2) {
        float acc = 0.f;
        #pragma unroll
        for (int m2 = 0; m2 < NRIM; ++m2) acc = fmaf(sS[n2][m2], vS[m2][t], acc);
        ctx[(b * NRIM + n2) * 1024 + h * CV + t] = __float2bfloat16(acc);
    }
}

// K5: out = mask ? ctx @ out_w[n] + hy : hs
__global__ __launch_bounds__(256)
void k5_out(const bf16* __restrict__ ctx, const float* __restrict__ out_w,
            const float* __restrict__ hy, const float* __restrict__ hs,
            const float* __restrict__ maskg, float* __restrict__ out)
{
    const int n  = blockIdx.x;
    const int b0 = blockIdx.y * 16;
    const int t  = threadIdx.x;

    __shared__ float cS[256][20];
    float acc[16];
    #pragma unroll
    for (int i = 0; i < 16; ++i) acc[i] = 0.f;

    const float* W = out_w + (size_t)n * 1024 * 256;
    for (int kc = 0; kc < 4; ++kc) {
        __syncthreads();
        for (int i = 0; i < 16; ++i)
            cS[t][i] = __bfloat162float(ctx[((b0 + i) * NRIM + n) * 1024 + kc * 256 + t]);
        __syncthreads();
        for (int kk = 0; kk < 256; ++kk) {
            float w = W[(size_t)(kc * 256 + kk) * 256 + t];
            const float4* crow = (const float4*)(&cS[kk][0]);
            #pragma unroll
            for (int g = 0; g < 4; ++g) {
                float4 c4 = crow[g];
                acc[4*g+0] = fmaf(c4.x, w, acc[4*g+0]);
                acc[4*g+1] = fmaf(c4.y, w, acc[4*g+1]);
                acc[4*g+2] = fmaf(c4.z, w, acc[4*g+2]);
                acc[4*g+3] = fmaf(c4.w, w, acc[4*g+3]);
            }
        }
    }

    #pragma unroll
    for (int i = 0; i < 16; ++i) {
        int b = b0 + i;
        float mk  = maskg[b * NRIM + n];
        float hyv = hy[(b * NRIM + n) * HID + t];
        float hsv = hs[(b * NRIM + n) * HID + t];
        out[(b * NRIM + n) * HID + t] = (mk > 0.5f) ? (acc[i] + hyv) : hsv;
    }
}

extern "C" void kernel_launch(void* const* d_in, const int* in_sizes, int n_in,
                              void* d_out, int out_size, void* d_ws, size_t ws_size,
                              hipStream_t stream) {
    const float* x       = (const float*)d_in[0];
    const float* hs      = (const float*)d_in[1];
    const float* option  = (const float*)d_in[2];
    const float* value_w = (const float*)d_in[3];
    const float* value_b = (const float*)d_in[4];
    const float* p_w     = (const float*)d_in[5];
    const float* p_b     = (const float*)d_in[6];
    const float* x2h_w   = (const float*)d_in[7];
    const float* h2h_w   = (const float*)d_in[8];
    const float* q_w     = (const float*)d_in[9];
    const float* k_w     = (const float*)d_in[10];
    const float* v_w     = (const float*)d_in[11];
    const float* out_w   = (const float*)d_in[12];
    float* out = (float*)d_out;

    size_t off = 0;
    auto carve = [&](size_t bytes) -> void* {
        void* p = (char*)d_ws + off;
        off += (bytes + 255) & ~(size_t)255;
        return p;
    };
    float* hy    = (float*)carve((size_t)BATCH * NRIM * HID * 4);
    float* qo    = (float*)carve((size_t)BATCH * NRIM * 128 * 4);
    float* ko    = (float*)carve((size_t)BATCH * NRIM * 128 * 4);
    bf16*  vo    = (bf16*) carve((size_t)BATCH * NRIM * 1024 * 2);
    bf16*  ctx   = (bf16*) carve((size_t)BATCH * NRIM * 1024 * 2);
    float* vl0   = (float*)carve((size_t)BATCH * VAL * 4);
    float* p0g   = (float*)carve((size_t)BATCH * NRIM * 4);
    float* maskg = (float*)carve((size_t)BATCH * NRIM * 4);

    k1_prep<<<dim3(BATCH), dim3(256), 0, stream>>>(x, option, value_w, value_b, p_w, p_b,
                                                   vl0, p0g, maskg);
    k2_gru<<<dim3(NRIM, BATCH / 16), dim3(256), 0, stream>>>(hs, vl0, p0g, maskg, value_b,
                                                             x2h_w, h2h_w, hy);
    k3_qkv<<<dim3(5, NRIM, BATCH / 16), dim3(256), 0, stream>>>(hy, q_w, k_w, v_w, qo, ko, vo);
    k4_attn<<<dim3(CH, BATCH), dim3(256), 0, stream>>>(qo, ko, vo, maskg, ctx);
    k5_out<<<dim3(NRIM, BATCH / 16), dim3(256), 0, stream>>>(ctx, out_w, hy, hs, maskg, out);
}

// Round 2
// 438.090 us; speedup vs baseline: 3.0766x; 3.0766x over previous
//
#include <hip/hip_runtime.h>
#include <hip/hip_bf16.h>
#include <math.h>

#define BATCH 2048
#define INDIM 512
#define HID   256
#define NRIM  16
#define VAL   400
#define ONUM  8
#define CH    4
#define CK    32
#define CV    256
#define KACT  8

typedef __hip_bfloat16 hbf;
typedef __attribute__((ext_vector_type(8))) __bf16 bf16x8;
typedef __attribute__((ext_vector_type(4))) float f32x4;

__device__ __forceinline__ float sigmoidf_(float x) { return 1.0f / (1.0f + expf(-x)); }

#define GLL(g, l) __builtin_amdgcn_global_load_lds(                                   \
    (const __attribute__((address_space(1))) void*)(g),                               \
    (__attribute__((address_space(3))) void*)(l), 16, 0, 0)

// ---------------- K1: scores, top-k mask, softmax p0, vl0 = x @ value_w + b -------
__global__ __launch_bounds__(256)
void k1_prep(const float* __restrict__ x, const float* __restrict__ option,
             const float* __restrict__ value_w, const float* __restrict__ value_b,
             const float* __restrict__ p_w, const float* __restrict__ p_b,
             float* __restrict__ vl0, float* __restrict__ p0g, float* __restrict__ maskg)
{
    const int b = blockIdx.x;
    const int t = threadIdx.x;
    __shared__ float xS[INDIM];
    __shared__ float sc[NRIM][2];

    xS[t]       = x[b * INDIM + t];
    xS[t + 256] = x[b * INDIM + t + 256];

    if (t < 32) {
        int n = t & 15, i = t >> 4;
        float s = (i == 0) ? p_b[n] : 0.0f;
        #pragma unroll
        for (int o = 0; o < ONUM; ++o)
            s = fmaf(option[(b * 2 + i) * ONUM + o], p_w[o * NRIM + n], s);
        sc[n][i] = s;
    }
    __syncthreads();

    if (t < NRIM) {
        int n = t;
        float s0 = sc[n][0], s1 = sc[n][1];
        int rank = 0;
        for (int m = 0; m < NRIM; ++m) {
            float sm = sc[m][0];
            if (sm > s0 || (sm == s0 && m < n)) rank++;
        }
        float mk = (rank < KACT) ? 1.0f : 0.0f;
        float mx = fmaxf(s0, s1);
        float e0 = expf(s0 - mx), e1 = expf(s1 - mx);
        p0g[b * NRIM + n]   = e0 / (e0 + e1);
        maskg[b * NRIM + n] = mk;
    }

    for (int c = t; c < VAL; c += 256) {
        float acc = value_b[c];
        for (int i = 0; i < INDIM; ++i)
            acc = fmaf(xS[i], value_w[i * VAL + c], acc);
        vl0[b * VAL + c] = acc;
    }
}

// ---------------- K1b: build A2[b][n][672] = [ bf16(hs) | masked inputs | 0 pad ] --
__global__ __launch_bounds__(256)
void k1b_a2(const float* __restrict__ hs, const float* __restrict__ vl0,
            const float* __restrict__ p0g, const float* __restrict__ maskg,
            const float* __restrict__ value_b, hbf* __restrict__ A2)
{
    const int b = blockIdx.x;
    const int t = threadIdx.x;
    __shared__ float vS[VAL];
    for (int j = t; j < VAL; j += 256) vS[j] = vl0[b * VAL + j];
    __syncthreads();

    for (int n = 0; n < NRIM; ++n) {
        size_t ro = ((size_t)b * NRIM + n) * 672;
        float p0 = p0g[b * NRIM + n], mk = maskg[b * NRIM + n];
        A2[ro + t] = __float2bfloat16(hs[((size_t)b * NRIM + n) * HID + t]);
        for (int j = t; j < VAL; j += 256)
            A2[ro + 256 + j] = __float2bfloat16(mk * (p0 * vS[j] + (1.0f - p0) * value_b[j]));
        if (t < 16) A2[ro + 656 + t] = __float2bfloat16(0.0f);
    }
}

// ---------------- zero fill (bf16, nelem multiple of 8) ----------------------------
__global__ __launch_bounds__(256)
void k_zero(hbf* __restrict__ p, long nelem8)
{
    long i = (long)blockIdx.x * 256 + threadIdx.x;
    if (i < nelem8) {
        uint4 z; z.x = 0; z.y = 0; z.z = 0; z.w = 0;
        ((uint4*)p)[i] = z;
    }
}

// ---------------- transpose+convert: dst[n][coff+cmap(c)][koff+k] = src[n][k][c] ---
__global__ __launch_bounds__(256)
void t_conv(const float* __restrict__ src, hbf* __restrict__ dst,
            int K, int C, long s_nstride, long d_nstride, int dstride,
            int koff, int coff, int cmode)
{
    const int n  = blockIdx.z;
    const int c0 = blockIdx.x * 32, k0 = blockIdx.y * 32;
    const int tx = threadIdx.x & 31, ty = threadIdx.x >> 5;
    __shared__ float tile[32][33];
    const float* s = src + (size_t)n * s_nstride;
    #pragma unroll
    for (int i = 0; i < 4; ++i) {
        int k = k0 + ty + i * 8, c = c0 + tx;
        tile[ty + i * 8][tx] = (k < K && c < C) ? s[(size_t)k * C + c] : 0.0f;
    }
    __syncthreads();
    hbf* d = dst + (size_t)n * d_nstride;
    #pragma unroll
    for (int i = 0; i < 4; ++i) {
        int c = c0 + ty + i * 8, k = k0 + tx;
        if (c < C && k < K) {
            int cc = coff + (cmode ? (c < 512 ? c : c + 256) : c);
            d[(size_t)cc * dstride + koff + k] = __float2bfloat16(tile[tx][ty + i * 8]);
        }
    }
}

// ---------------- MFMA GEMM core: C[128x128] += A[128xK] * B^T[128xK] --------------
__device__ __forceinline__ void gemm_core(const hbf* __restrict__ A, int lda,
                                          const hbf* __restrict__ B, int ldb,
                                          int K, short* As, short* Bs, f32x4 acc[4][4])
{
    const int t = threadIdx.x;
    const int w = t >> 6, lane = t & 63, l15 = lane & 15, l4 = lane >> 4;
    const int wr = w >> 1, wc = w & 1;
    const int crow = t >> 2, ccol = (t & 3) * 8;
    short* AsW = As + w * 512;   // wave-uniform 1KB LDS region
    short* BsW = Bs + w * 512;

    for (int kk = 0; kk < K; kk += 32) {
        const hbf* ga0 = A + (size_t)crow * lda + kk + ccol;
        const hbf* ga1 = A + (size_t)(crow + 64) * lda + kk + ccol;
        const hbf* gb0 = B + (size_t)crow * ldb + kk + ccol;
        const hbf* gb1 = B + (size_t)(crow + 64) * ldb + kk + ccol;
        __syncthreads();
        GLL(ga0, AsW);
        GLL(ga1, AsW + 2048);
        GLL(gb0, BsW);
        GLL(gb1, BsW + 2048);
        __syncthreads();

        bf16x8 af[4], bfr[4];
        #pragma unroll
        for (int m = 0; m < 4; ++m)
            af[m] = *(const bf16x8*)(As + (wr * 64 + m * 16 + l15) * 32 + l4 * 8);
        #pragma unroll
        for (int nb = 0; nb < 4; ++nb)
            bfr[nb] = *(const bf16x8*)(Bs + (wc * 64 + nb * 16 + l15) * 32 + l4 * 8);
        #pragma unroll
        for (int m = 0; m < 4; ++m)
            #pragma unroll
            for (int nb = 0; nb < 4; ++nb)
                acc[m][nb] = __builtin_amdgcn_mfma_f32_16x16x32_bf16(af[m], bfr[nb], acc[m][nb], 0, 0, 0);
    }
}

// ---------------- K2 GEMM: g[b][n][1024] = A2[b][n][:] @ W2[n][c][:]^T -------------
__global__ __launch_bounds__(256)
void k2g(const hbf* __restrict__ A2, const hbf* __restrict__ W2, hbf* __restrict__ g)
{
    __shared__ __align__(16) short As[128 * 32];
    __shared__ __align__(16) short Bs[128 * 32];
    const int c0 = blockIdx.x * 128, m0 = blockIdx.y * 128, n = blockIdx.z;
    const hbf* A = A2 + (size_t)n * 672 + (size_t)m0 * (NRIM * 672);
    const hbf* B = W2 + (size_t)n * (1024 * 672) + (size_t)c0 * 672;

    f32x4 acc[4][4];
    f32x4 zz = {0.0f, 0.0f, 0.0f, 0.0f};
    #pragma unroll
    for (int m = 0; m < 4; ++m)
        #pragma unroll
        for (int nb = 0; nb < 4; ++nb) acc[m][nb] = zz;

    gemm_core(A, NRIM * 672, B, 672, 672, As, Bs, acc);

    const int t = threadIdx.x;
    const int w = t >> 6, lane = t & 63, l15 = lane & 15, l4 = lane >> 4;
    const int wr = w >> 1, wc = w & 1;
    #pragma unroll
    for (int m = 0; m < 4; ++m)
        #pragma unroll
        for (int nb = 0; nb < 4; ++nb) {
            int col = c0 + wc * 64 + nb * 16 + l15;
            #pragma unroll
            for (int j = 0; j < 4; ++j) {
                int row = m0 + wr * 64 + m * 16 + l4 * 4 + j;
                g[((size_t)row * NRIM + n) * 1024 + col] = __float2bfloat16(acc[m][nb][j]);
            }
        }
}

// ---------------- GRU elementwise epilogue -----------------------------------------
__global__ __launch_bounds__(256)
void k_gru_ep(const hbf* __restrict__ g, const float* __restrict__ hs, hbf* __restrict__ hyB)
{
    const size_t row = blockIdx.x;
    const int t = threadIdx.x;
    const hbf* gr = g + row * 1024;
    float r  = __bfloat162float(gr[t]);
    float ig = __bfloat162float(gr[t + 256]);
    float xn = __bfloat162float(gr[t + 512]);
    float hn = __bfloat162float(gr[t + 768]);
    float reset = sigmoidf_(r);
    float inp   = sigmoidf_(ig);
    float newg  = tanhf(xn + reset * hn);
    float h     = hs[row * HID + t];
    hyB[row * HID + t] = __float2bfloat16(newg + inp * (h - newg));
}

// ---------------- K3 GEMM: qkv[b][n][1280] = hy @ Wqkv^T ---------------------------
__global__ __launch_bounds__(256)
void k3g(const hbf* __restrict__ hyB, const hbf* __restrict__ Wqkv, hbf* __restrict__ qkv)
{
    __shared__ __align__(16) short As[128 * 32];
    __shared__ __align__(16) short Bs[128 * 32];
    const int c0 = blockIdx.x * 128, m0 = blockIdx.y * 128, n = blockIdx.z;
    const hbf* A = hyB + (size_t)n * HID + (size_t)m0 * (NRIM * HID);
    const hbf* B = Wqkv + (size_t)n * (1280 * 256) + (size_t)c0 * 256;

    f32x4 acc[4][4];
    f32x4 zz = {0.0f, 0.0f, 0.0f, 0.0f};
    #pragma unroll
    for (int m = 0; m < 4; ++m)
        #pragma unroll
        for (int nb = 0; nb < 4; ++nb) acc[m][nb] = zz;

    gemm_core(A, NRIM * HID, B, 256, 256, As, Bs, acc);

    const int t = threadIdx.x;
    const int w = t >> 6, lane = t & 63, l15 = lane & 15, l4 = lane >> 4;
    const int wr = w >> 1, wc = w & 1;
    #pragma unroll
    for (int m = 0; m < 4; ++m)
        #pragma unroll
        for (int nb = 0; nb < 4; ++nb) {
            int col = c0 + wc * 64 + nb * 16 + l15;
            #pragma unroll
            for (int j = 0; j < 4; ++j) {
                int row = m0 + wr * 64 + m * 16 + l4 * 4 + j;
                qkv[((size_t)row * NRIM + n) * 1280 + col] = __float2bfloat16(acc[m][nb][j]);
            }
        }
}

// ---------------- K4: attention per (h, b) -----------------------------------------
__global__ __launch_bounds__(256)
void k4_attn(const hbf* __restrict__ qkv, const float* __restrict__ maskg,
             hbf* __restrict__ ctx)
{
    const int h = blockIdx.x;
    const int b = blockIdx.y;
    const int t = threadIdx.x;

    __shared__ float qS[NRIM][33], kS[NRIM][33];
    __shared__ float sS[NRIM][17];
    __shared__ float vS[NRIM][CV];
    __shared__ float mS[NRIM];

    for (int idx = t; idx < NRIM * CK; idx += 256) {
        int n2 = idx >> 5, i = idx & 31;
        size_t base = ((size_t)b * NRIM + n2) * 1280;
        qS[n2][i] = __bfloat162float(qkv[base + h * CK + i]);
        kS[n2][i] = __bfloat162float(qkv[base + 128 + h * CK + i]);
    }
    for (int idx = t; idx < NRIM * CV; idx += 256) {
        int m2 = idx >> 8, c = idx & 255;
        vS[m2][c] = __bfloat162float(qkv[((size_t)b * NRIM + m2) * 1280 + 256 + h * CV + c]);
    }
    if (t < NRIM) mS[t] = maskg[b * NRIM + t];
    __syncthreads();

    {
        int nn = t >> 4, mm = t & 15;
        float s = 0.f;
        #pragma unroll
        for (int i = 0; i < CK; ++i) s = fmaf(qS[nn][i], kS[mm][i], s);
        sS[nn][mm] = s * 0.17677669529663687f;
    }
    __syncthreads();

    if (t < NRIM) {
        float mx = -1e30f;
        #pragma unroll
        for (int m2 = 0; m2 < NRIM; ++m2) mx = fmaxf(mx, sS[t][m2]);
        float sum = 0.f;
        #pragma unroll
        for (int m2 = 0; m2 < NRIM; ++m2) { float e = expf(sS[t][m2] - mx); sS[t][m2] = e; sum += e; }
        float inv = mS[t] / sum;
        #pragma unroll
        for (int m2 = 0; m2 < NRIM; ++m2) sS[t][m2] *= inv;
    }
    __syncthreads();

    for (int n2 = 0; n2 < NRIM; ++n2) {
        float acc = 0.f;
        #pragma unroll
        for (int m2 = 0; m2 < NRIM; ++m2) acc = fmaf(sS[n2][m2], vS[m2][t], acc);
        ctx[((size_t)b * NRIM + n2) * 1024 + h * CV + t] = __float2bfloat16(acc);
    }
}

// ---------------- K5 GEMM: out = mask ? ctx @ Wout^T + hy : hs ---------------------
__global__ __launch_bounds__(256)
void k5g(const hbf* __restrict__ ctx, const hbf* __restrict__ Wout,
         const hbf* __restrict__ hyB, const float* __restrict__ hs,
         const float* __restrict__ maskg, float* __restrict__ out)
{
    __shared__ __align__(16) short As[128 * 32];
    __shared__ __align__(16) short Bs[128 * 32];
    const int c0 = blockIdx.x * 128, m0 = blockIdx.y * 128, n = blockIdx.z;
    const hbf* A = ctx + (size_t)n * 1024 + (size_t)m0 * (NRIM * 1024);
    const hbf* B = Wout + (size_t)n * (256 * 1024) + (size_t)c0 * 1024;

    f32x4 acc[4][4];
    f32x4 zz = {0.0f, 0.0f, 0.0f, 0.0f};
    #pragma unroll
    for (int m = 0; m < 4; ++m)
        #pragma unroll
        for (int nb = 0; nb < 4; ++nb) acc[m][nb] = zz;

    gemm_core(A, NRIM * 1024, B, 1024, 1024, As, Bs, acc);

    const int t = threadIdx.x;
    const int w = t >> 6, lane = t & 63, l15 = lane & 15, l4 = lane >> 4;
    const int wr = w >> 1, wc = w & 1;
    #pragma unroll
    for (int m = 0; m < 4; ++m)
        #pragma unroll
        for (int nb = 0; nb < 4; ++nb) {
            int col = c0 + wc * 64 + nb * 16 + l15;
            #pragma unroll
            for (int j = 0; j < 4; ++j) {
                int row = m0 + wr * 64 + m * 16 + l4 * 4 + j;
                size_t idx = ((size_t)row * NRIM + n) * HID + col;
                float mk = maskg[row * NRIM + n];
                out[idx] = (mk > 0.5f) ? (acc[m][nb][j] + __bfloat162float(hyB[idx]))
                                       : hs[idx];
            }
        }
}

extern "C" void kernel_launch(void* const* d_in, const int* in_sizes, int n_in,
                              void* d_out, int out_size, void* d_ws, size_t ws_size,
                              hipStream_t stream) {
    const float* x       = (const float*)d_in[0];
    const float* hs      = (const float*)d_in[1];
    const float* option  = (const float*)d_in[2];
    const float* value_w = (const float*)d_in[3];
    const float* value_b = (const float*)d_in[4];
    const float* p_w     = (const float*)d_in[5];
    const float* p_b     = (const float*)d_in[6];
    const float* x2h_w   = (const float*)d_in[7];
    const float* h2h_w   = (const float*)d_in[8];
    const float* q_w     = (const float*)d_in[9];
    const float* k_w     = (const float*)d_in[10];
    const float* v_w     = (const float*)d_in[11];
    const float* out_w   = (const float*)d_in[12];
    float* out = (float*)d_out;

    char* ws = (char*)d_ws;
    // region0: A2 (44 MB) / ctx (67 MB) union
    hbf* A2   = (hbf*)(ws);
    hbf* ctx  = (hbf*)(ws);
    size_t off = 67108864;
    // region1: g (67 MB) / qkv (84 MB) union
    hbf* g    = (hbf*)(ws + off);
    hbf* qkv  = (hbf*)(ws + off);
    off += 83886080;
    hbf* W2   = (hbf*)(ws + off); off += 22020096;   // [16][1024][672]
    hbf* Wqkv = (hbf*)(ws + off); off += 10485760;   // [16][1280][256]
    hbf* Wout = (hbf*)(ws + off); off += 8388608;    // [16][256][1024]
    hbf* hyB  = (hbf*)(ws + off); off += 16777216;   // [32768][256]
    float* vl0   = (float*)(ws + off); off += 3276800;
    float* p0g   = (float*)(ws + off); off += 131072;
    float* maskg = (float*)(ws + off); off += 131072;

    // --- weight conversion (transpose to [cols][K], bf16) ---
    k_zero<<<dim3(5376), dim3(256), 0, stream>>>(W2, 1376256L);
    t_conv<<<dim3(24, 8, 16), dim3(256), 0, stream>>>(h2h_w, W2, 256, 768,
            196608L, 688128L, 672, 0, 0, 1);
    t_conv<<<dim3(24, 13, 16), dim3(256), 0, stream>>>(x2h_w, W2, 400, 768,
            307200L, 688128L, 672, 256, 0, 0);
    t_conv<<<dim3(4, 8, 16), dim3(256), 0, stream>>>(q_w, Wqkv, 256, 128,
            32768L, 327680L, 256, 0, 0, 0);
    t_conv<<<dim3(4, 8, 16), dim3(256), 0, stream>>>(k_w, Wqkv, 256, 128,
            32768L, 327680L, 256, 0, 128, 0);
    t_conv<<<dim3(32, 8, 16), dim3(256), 0, stream>>>(v_w, Wqkv, 256, 1024,
            262144L, 327680L, 256, 0, 256, 0);
    t_conv<<<dim3(8, 32, 16), dim3(256), 0, stream>>>(out_w, Wout, 1024, 256,
            262144L, 262144L, 1024, 0, 0, 0);

    // --- gating + inputs ---
    k1_prep<<<dim3(BATCH), dim3(256), 0, stream>>>(x, option, value_w, value_b, p_w, p_b,
                                                   vl0, p0g, maskg);
    k1b_a2<<<dim3(BATCH), dim3(256), 0, stream>>>(hs, vl0, p0g, maskg, value_b, A2);

    // --- GRU gates GEMM + elementwise ---
    k2g<<<dim3(8, 16, 16), dim3(256), 0, stream>>>(A2, W2, g);
    k_gru_ep<<<dim3(BATCH * NRIM), dim3(256), 0, stream>>>(g, hs, hyB);

    // --- QKV GEMM ---
    k3g<<<dim3(10, 16, 16), dim3(256), 0, stream>>>(hyB, Wqkv, qkv);

    // --- attention ---
    k4_attn<<<dim3(CH, BATCH), dim3(256), 0, stream>>>(qkv, maskg, ctx);

    // --- output projection GEMM (fused mask/residual) ---
    k5g<<<dim3(2, 16, 16), dim3(256), 0, stream>>>(ctx, Wout, hyB, hs, maskg, out);
}

// Round 3
// 411.577 us; speedup vs baseline: 3.2748x; 1.0644x over previous
//
#include <hip/hip_runtime.h>
#include <hip/hip_bf16.h>
#include <math.h>

#define BATCH 2048
#define INDIM 512
#define HID   256
#define NRIM  16
#define VAL   400
#define ONUM  8
#define CH    4
#define CK    32
#define CV    256
#define KACT  8
#define K2P   704   // GRU K padded to multiple of 64 (672 -> 704)

typedef __hip_bfloat16 hbf;
typedef __attribute__((ext_vector_type(8))) __bf16 bf16x8;
typedef __attribute__((ext_vector_type(4))) float f32x4;

__device__ __forceinline__ float sigmoidf_(float x) { return 1.0f / (1.0f + expf(-x)); }

#define GLL(g, l) __builtin_amdgcn_global_load_lds(                                   \
    (const __attribute__((address_space(1))) void*)(g),                               \
    (__attribute__((address_space(3))) void*)(l), 16, 0, 0)

// ---------------- K1: scores, top-k mask, softmax p0, vl0 = x @ value_w + b -------
__global__ __launch_bounds__(256)
void k1_prep(const float* __restrict__ x, const float* __restrict__ option,
             const float* __restrict__ value_w, const float* __restrict__ value_b,
             const float* __restrict__ p_w, const float* __restrict__ p_b,
             float* __restrict__ vl0, float* __restrict__ p0g, float* __restrict__ maskg)
{
    const int b = blockIdx.x;
    const int t = threadIdx.x;
    __shared__ float xS[INDIM];
    __shared__ float sc[NRIM][2];

    xS[t]       = x[b * INDIM + t];
    xS[t + 256] = x[b * INDIM + t + 256];

    if (t < 32) {
        int n = t & 15, i = t >> 4;
        float s = (i == 0) ? p_b[n] : 0.0f;
        #pragma unroll
        for (int o = 0; o < ONUM; ++o)
            s = fmaf(option[(b * 2 + i) * ONUM + o], p_w[o * NRIM + n], s);
        sc[n][i] = s;
    }
    __syncthreads();

    if (t < NRIM) {
        int n = t;
        float s0 = sc[n][0], s1 = sc[n][1];
        int rank = 0;
        for (int m = 0; m < NRIM; ++m) {
            float sm = sc[m][0];
            if (sm > s0 || (sm == s0 && m < n)) rank++;
        }
        float mk = (rank < KACT) ? 1.0f : 0.0f;
        float mx = fmaxf(s0, s1);
        float e0 = expf(s0 - mx), e1 = expf(s1 - mx);
        p0g[b * NRIM + n]   = e0 / (e0 + e1);
        maskg[b * NRIM + n] = mk;
    }

    for (int c = t; c < VAL; c += 256) {
        float acc = value_b[c];
        for (int i = 0; i < INDIM; ++i)
            acc = fmaf(xS[i], value_w[i * VAL + c], acc);
        vl0[b * VAL + c] = acc;
    }
}

// ---------------- K1b: A2[b][n][K2P] = [ bf16(hs) | masked inputs | 0 pad ] --------
__global__ __launch_bounds__(256)
void k1b_a2(const float* __restrict__ hs, const float* __restrict__ vl0,
            const float* __restrict__ p0g, const float* __restrict__ maskg,
            const float* __restrict__ value_b, hbf* __restrict__ A2)
{
    const int b = blockIdx.x;
    const int t = threadIdx.x;
    __shared__ float vS[VAL];
    for (int j = t; j < VAL; j += 256) vS[j] = vl0[b * VAL + j];
    __syncthreads();

    for (int n = 0; n < NRIM; ++n) {
        size_t ro = ((size_t)b * NRIM + n) * K2P;
        float p0 = p0g[b * NRIM + n], mk = maskg[b * NRIM + n];
        A2[ro + t] = __float2bfloat16(hs[((size_t)b * NRIM + n) * HID + t]);
        for (int j = t; j < VAL; j += 256)
            A2[ro + 256 + j] = __float2bfloat16(mk * (p0 * vS[j] + (1.0f - p0) * value_b[j]));
        if (t < 48) A2[ro + 656 + t] = __float2bfloat16(0.0f);
    }
}

// ---------------- zero fill (bf16, nelem8 = count of 16B chunks) -------------------
__global__ __launch_bounds__(256)
void k_zero(hbf* __restrict__ p, long nelem8)
{
    long i = (long)blockIdx.x * 256 + threadIdx.x;
    if (i < nelem8) {
        uint4 z; z.x = 0; z.y = 0; z.z = 0; z.w = 0;
        ((uint4*)p)[i] = z;
    }
}

// ---------------- transpose+convert: dst[n][coff+cmap(c)][koff+k] = src[n][k][c] ---
__global__ __launch_bounds__(256)
void t_conv(const float* __restrict__ src, hbf* __restrict__ dst,
            int K, int C, long s_nstride, long d_nstride, int dstride,
            int koff, int coff, int cmode)
{
    const int n  = blockIdx.z;
    const int c0 = blockIdx.x * 32, k0 = blockIdx.y * 32;
    const int tx = threadIdx.x & 31, ty = threadIdx.x >> 5;
    __shared__ float tile[32][33];
    const float* s = src + (size_t)n * s_nstride;
    #pragma unroll
    for (int i = 0; i < 4; ++i) {
        int k = k0 + ty + i * 8, c = c0 + tx;
        tile[ty + i * 8][tx] = (k < K && c < C) ? s[(size_t)k * C + c] : 0.0f;
    }
    __syncthreads();
    hbf* d = dst + (size_t)n * d_nstride;
    #pragma unroll
    for (int i = 0; i < 4; ++i) {
        int c = c0 + ty + i * 8, k = k0 + tx;
        if (c < C && k < K) {
            int cc = coff + (cmode ? (c < 512 ? c : c + 256) : c);
            d[(size_t)cc * dstride + koff + k] = __float2bfloat16(tile[tx][ty + i * 8]);
        }
    }
}

// ------ MFMA GEMM core: BK=64, swizzled LDS (pre-swizzled global src, rule #21) ----
// C[128x128] += A[128xK] * B^T[128xK]; As/Bs = [128][64] shorts (16KB each).
__device__ __forceinline__ void gemm_core64(const hbf* __restrict__ A, long lda,
                                            const hbf* __restrict__ B, long ldb,
                                            int K, short* As, short* Bs, f32x4 acc[4][4])
{
    const int t = threadIdx.x;
    const int w = t >> 6, lane = t & 63;
    const int l15 = lane & 15, l4 = lane >> 4;
    const int rl = lane >> 3;                 // row within this wave's 8-row group
    const int gu = (lane & 7) ^ rl;           // pre-swizzled source 16B-unit
    const int l7 = l15 & 7;

    for (int kk = 0; kk < K; kk += 64) {
        __syncthreads();
        #pragma unroll
        for (int q = 0; q < 4; ++q) {
            int row = q * 32 + w * 8 + rl;
            GLL(A + (size_t)row * lda + kk + gu * 8, As + (q * 32 + w * 8) * 64);
            GLL(B + (size_t)row * ldb + kk + gu * 8, Bs + (q * 32 + w * 8) * 64);
        }
        __syncthreads();

        const int wr = w >> 1, wc = w & 1;
        #pragma unroll
        for (int ks = 0; ks < 2; ++ks) {
            const int p = (ks * 4 + l4) ^ l7;  // swizzled read unit
            bf16x8 af[4], bfr[4];
            #pragma unroll
            for (int m = 0; m < 4; ++m)
                af[m] = *(const bf16x8*)(As + (wr * 64 + m * 16 + l15) * 64 + p * 8);
            #pragma unroll
            for (int nb = 0; nb < 4; ++nb)
                bfr[nb] = *(const bf16x8*)(Bs + (wc * 64 + nb * 16 + l15) * 64 + p * 8);
            #pragma unroll
            for (int m = 0; m < 4; ++m)
                #pragma unroll
                for (int nb = 0; nb < 4; ++nb)
                    acc[m][nb] = __builtin_amdgcn_mfma_f32_16x16x32_bf16(af[m], bfr[nb], acc[m][nb], 0, 0, 0);
        }
    }
}

// ---------------- K2 GEMM: g[b][n][1024] = A2[b][n][:] @ W2[n][c][:]^T -------------
__global__ __launch_bounds__(256)
void k2g(const hbf* __restrict__ A2, const hbf* __restrict__ W2, hbf* __restrict__ g)
{
    __shared__ __align__(16) short As[128 * 64];
    __shared__ __align__(16) short Bs[128 * 64];
    // XCD-aware bijective swizzle: 2048 blocks, one n-slice (128 blocks) per XCD chunk
    const int id = blockIdx.x;
    const int xcd = id & 7, idx = id >> 3;
    const int n  = xcd + ((idx >> 7) << 3);
    const int rem = idx & 127;
    const int m0 = (rem >> 3) * 128;
    const int c0 = (rem & 7) * 128;

    const hbf* A = A2 + (size_t)n * K2P + (size_t)m0 * (NRIM * K2P);
    const hbf* B = W2 + (size_t)n * (1024 * K2P) + (size_t)c0 * K2P;

    f32x4 acc[4][4];
    f32x4 zz = {0.0f, 0.0f, 0.0f, 0.0f};
    #pragma unroll
    for (int m = 0; m < 4; ++m)
        #pragma unroll
        for (int nb = 0; nb < 4; ++nb) acc[m][nb] = zz;

    gemm_core64(A, NRIM * K2P, B, K2P, K2P, As, Bs, acc);

    const int t = threadIdx.x;
    const int w = t >> 6, lane = t & 63, l15 = lane & 15, l4 = lane >> 4;
    const int wr = w >> 1, wc = w & 1;
    #pragma unroll
    for (int m = 0; m < 4; ++m)
        #pragma unroll
        for (int nb = 0; nb < 4; ++nb) {
            int col = c0 + wc * 64 + nb * 16 + l15;
            #pragma unroll
            for (int j = 0; j < 4; ++j) {
                int row = m0 + wr * 64 + m * 16 + l4 * 4 + j;
                g[((size_t)row * NRIM + n) * 1024 + col] = __float2bfloat16(acc[m][nb][j]);
            }
        }
}

// ---------------- GRU elementwise epilogue -----------------------------------------
__global__ __launch_bounds__(256)
void k_gru_ep(const hbf* __restrict__ g, const float* __restrict__ hs, hbf* __restrict__ hyB)
{
    const size_t row = blockIdx.x;
    const int t = threadIdx.x;
    const hbf* gr = g + row * 1024;
    float r  = __bfloat162float(gr[t]);
    float ig = __bfloat162float(gr[t + 256]);
    float xn = __bfloat162float(gr[t + 512]);
    float hn = __bfloat162float(gr[t + 768]);
    float reset = sigmoidf_(r);
    float inp   = sigmoidf_(ig);
    float newg  = tanhf(xn + reset * hn);
    float h     = hs[row * HID + t];
    hyB[row * HID + t] = __float2bfloat16(newg + inp * (h - newg));
}

// ---------------- K3 GEMM: qkv[b][n][1280] = hy @ Wqkv^T ---------------------------
__global__ __launch_bounds__(256)
void k3g(const hbf* __restrict__ hyB, const hbf* __restrict__ Wqkv, hbf* __restrict__ qkv)
{
    __shared__ __align__(16) short As[128 * 64];
    __shared__ __align__(16) short Bs[128 * 64];
    // 2560 blocks: per XCD, chunks of one n-slice (160 blocks)
    const int id = blockIdx.x;
    const int xcd = id & 7, idx = id >> 3;          // idx in [0,320)
    const int n  = xcd + (idx / 160) * 8;
    const int rem = idx % 160;
    const int m0 = (rem / 10) * 128;
    const int c0 = (rem % 10) * 128;

    const hbf* A = hyB + (size_t)n * HID + (size_t)m0 * (NRIM * HID);
    const hbf* B = Wqkv + (size_t)n * (1280 * 256) + (size_t)c0 * 256;

    f32x4 acc[4][4];
    f32x4 zz = {0.0f, 0.0f, 0.0f, 0.0f};
    #pragma unroll
    for (int m = 0; m < 4; ++m)
        #pragma unroll
        for (int nb = 0; nb < 4; ++nb) acc[m][nb] = zz;

    gemm_core64(A, NRIM * HID, B, 256, 256, As, Bs, acc);

    const int t = threadIdx.x;
    const int w = t >> 6, lane = t & 63, l15 = lane & 15, l4 = lane >> 4;
    const int wr = w >> 1, wc = w & 1;
    #pragma unroll
    for (int m = 0; m < 4; ++m)
        #pragma unroll
        for (int nb = 0; nb < 4; ++nb) {
            int col = c0 + wc * 64 + nb * 16 + l15;
            #pragma unroll
            for (int j = 0; j < 4; ++j) {
                int row = m0 + wr * 64 + m * 16 + l4 * 4 + j;
                qkv[((size_t)row * NRIM + n) * 1280 + col] = __float2bfloat16(acc[m][nb][j]);
            }
        }
}

// ---------------- K4: attention per (h, b) -----------------------------------------
__global__ __launch_bounds__(256)
void k4_attn(const hbf* __restrict__ qkv, const float* __restrict__ maskg,
             hbf* __restrict__ ctx)
{
    const int h = blockIdx.x;
    const int b = blockIdx.y;
    const int t = threadIdx.x;

    __shared__ float qS[NRIM][33], kS[NRIM][33];
    __shared__ float sS[NRIM][17];
    __shared__ float vS[NRIM][CV];
    __shared__ float mS[NRIM];

    for (int idx = t; idx < NRIM * CK; idx += 256) {
        int n2 = idx >> 5, i = idx & 31;
        size_t base = ((size_t)b * NRIM + n2) * 1280;
        qS[n2][i] = __bfloat162float(qkv[base + h * CK + i]);
        kS[n2][i] = __bfloat162float(qkv[base + 128 + h * CK + i]);
    }
    for (int idx = t; idx < NRIM * CV; idx += 256) {
        int m2 = idx >> 8, c = idx & 255;
        vS[m2][c] = __bfloat162float(qkv[((size_t)b * NRIM + m2) * 1280 + 256 + h * CV + c]);
    }
    if (t < NRIM) mS[t] = maskg[b * NRIM + t];
    __syncthreads();

    {
        int nn = t >> 4, mm = t & 15;
        float s = 0.f;
        #pragma unroll
        for (int i = 0; i < CK; ++i) s = fmaf(qS[nn][i], kS[mm][i], s);
        sS[nn][mm] = s * 0.17677669529663687f;
    }
    __syncthreads();

    if (t < NRIM) {
        float mx = -1e30f;
        #pragma unroll
        for (int m2 = 0; m2 < NRIM; ++m2) mx = fmaxf(mx, sS[t][m2]);
        float sum = 0.f;
        #pragma unroll
        for (int m2 = 0; m2 < NRIM; ++m2) { float e = expf(sS[t][m2] - mx); sS[t][m2] = e; sum += e; }
        float inv = mS[t] / sum;
        #pragma unroll
        for (int m2 = 0; m2 < NRIM; ++m2) sS[t][m2] *= inv;
    }
    __syncthreads();

    for (int n2 = 0; n2 < NRIM; ++n2) {
        float acc = 0.f;
        #pragma unroll
        for (int m2 = 0; m2 < NRIM; ++m2) acc = fmaf(sS[n2][m2], vS[m2][t], acc);
        ctx[((size_t)b * NRIM + n2) * 1024 + h * CV + t] = __float2bfloat16(acc);
    }
}

// ---------------- K5 GEMM: out = mask ? ctx @ Wout^T + hy : hs ---------------------
__global__ __launch_bounds__(256)
void k5g(const hbf* __restrict__ ctx, const hbf* __restrict__ Wout,
         const hbf* __restrict__ hyB, const float* __restrict__ hs,
         const float* __restrict__ maskg, float* __restrict__ out)
{
    __shared__ __align__(16) short As[128 * 64];
    __shared__ __align__(16) short Bs[128 * 64];
    // 512 blocks: per XCD, one n-slice = 32 blocks
    const int id = blockIdx.x;
    const int xcd = id & 7, idx = id >> 3;          // idx in [0,64)
    const int n  = xcd + ((idx >> 5) << 3);
    const int rem = idx & 31;
    const int m0 = (rem >> 1) * 128;
    const int c0 = (rem & 1) * 128;

    const hbf* A = ctx + (size_t)n * 1024 + (size_t)m0 * (NRIM * 1024);
    const hbf* B = Wout + (size_t)n * (256 * 1024) + (size_t)c0 * 1024;

    f32x4 acc[4][4];
    f32x4 zz = {0.0f, 0.0f, 0.0f, 0.0f};
    #pragma unroll
    for (int m = 0; m < 4; ++m)
        #pragma unroll
        for (int nb = 0; nb < 4; ++nb) acc[m][nb] = zz;

    gemm_core64(A, NRIM * 1024, B, 1024, 1024, As, Bs, acc);

    const int t = threadIdx.x;
    const int w = t >> 6, lane = t & 63, l15 = lane & 15, l4 = lane >> 4;
    const int wr = w >> 1, wc = w & 1;
    #pragma unroll
    for (int m = 0; m < 4; ++m)
        #pragma unroll
        for (int nb = 0; nb < 4; ++nb) {
            int col = c0 + wc * 64 + nb * 16 + l15;
            #pragma unroll
            for (int j = 0; j < 4; ++j) {
                int row = m0 + wr * 64 + m * 16 + l4 * 4 + j;
                size_t idx2 = ((size_t)row * NRIM + n) * HID + col;
                float mk = maskg[row * NRIM + n];
                out[idx2] = (mk > 0.5f) ? (acc[m][nb][j] + __bfloat162float(hyB[idx2]))
                                        : hs[idx2];
            }
        }
}

extern "C" void kernel_launch(void* const* d_in, const int* in_sizes, int n_in,
                              void* d_out, int out_size, void* d_ws, size_t ws_size,
                              hipStream_t stream) {
    const float* x       = (const float*)d_in[0];
    const float* hs      = (const float*)d_in[1];
    const float* option  = (const float*)d_in[2];
    const float* value_w = (const float*)d_in[3];
    const float* value_b = (const float*)d_in[4];
    const float* p_w     = (const float*)d_in[5];
    const float* p_b     = (const float*)d_in[6];
    const float* x2h_w   = (const float*)d_in[7];
    const float* h2h_w   = (const float*)d_in[8];
    const float* q_w     = (const float*)d_in[9];
    const float* k_w     = (const float*)d_in[10];
    const float* v_w     = (const float*)d_in[11];
    const float* out_w   = (const float*)d_in[12];
    float* out = (float*)d_out;

    char* ws = (char*)d_ws;
    // region0: A2 (46.1 MB, [2048][16][704]) / ctx (67 MB) union
    hbf* A2   = (hbf*)(ws);
    hbf* ctx  = (hbf*)(ws);
    size_t off = 67108864;
    // region1: g (67 MB) / qkv (84 MB) union
    hbf* g    = (hbf*)(ws + off);
    hbf* qkv  = (hbf*)(ws + off);
    off += 83886080;
    hbf* W2   = (hbf*)(ws + off); off += 23068672;   // [16][1024][704]
    hbf* Wqkv = (hbf*)(ws + off); off += 10485760;   // [16][1280][256]
    hbf* Wout = (hbf*)(ws + off); off += 8388608;    // [16][256][1024]
    hbf* hyB  = (hbf*)(ws + off); off += 16777216;   // [32768][256]
    float* vl0   = (float*)(ws + off); off += 3276800;
    float* p0g   = (float*)(ws + off); off += 131072;
    float* maskg = (float*)(ws + off); off += 131072;

    // --- weight conversion (transpose to [cols][K2P], bf16) ---
    k_zero<<<dim3(5632), dim3(256), 0, stream>>>(W2, 1441792L);
    t_conv<<<dim3(24, 8, 16), dim3(256), 0, stream>>>(h2h_w, W2, 256, 768,
            196608L, 720896L, K2P, 0, 0, 1);
    t_conv<<<dim3(24, 13, 16), dim3(256), 0, stream>>>(x2h_w, W2, 400, 768,
            307200L, 720896L, K2P, 256, 0, 0);
    t_conv<<<dim3(4, 8, 16), dim3(256), 0, stream>>>(q_w, Wqkv, 256, 128,
            32768L, 327680L, 256, 0, 0, 0);
    t_conv<<<dim3(4, 8, 16), dim3(256), 0, stream>>>(k_w, Wqkv, 256, 128,
            32768L, 327680L, 256, 0, 128, 0);
    t_conv<<<dim3(32, 8, 16), dim3(256), 0, stream>>>(v_w, Wqkv, 256, 1024,
            262144L, 327680L, 256, 0, 256, 0);
    t_conv<<<dim3(8, 32, 16), dim3(256), 0, stream>>>(out_w, Wout, 1024, 256,
            262144L, 262144L, 1024, 0, 0, 0);

    // --- gating + inputs ---
    k1_prep<<<dim3(BATCH), dim3(256), 0, stream>>>(x, option, value_w, value_b, p_w, p_b,
                                                   vl0, p0g, maskg);
    k1b_a2<<<dim3(BATCH), dim3(256), 0, stream>>>(hs, vl0, p0g, maskg, value_b, A2);

    // --- GRU gates GEMM + elementwise ---
    k2g<<<dim3(2048), dim3(256), 0, stream>>>(A2, W2, g);
    k_gru_ep<<<dim3(BATCH * NRIM), dim3(256), 0, stream>>>(g, hs, hyB);

    // --- QKV GEMM ---
    k3g<<<dim3(2560), dim3(256), 0, stream>>>(hyB, Wqkv, qkv);

    // --- attention ---
    k4_attn<<<dim3(CH, BATCH), dim3(256), 0, stream>>>(qkv, maskg, ctx);

    // --- output projection GEMM (fused mask/residual) ---
    k5g<<<dim3(512), dim3(256), 0, stream>>>(ctx, Wout, hyB, hs, maskg, out);
}

// Round 4
// 345.698 us; speedup vs baseline: 3.8988x; 1.1906x over previous
//
#include <hip/hip_runtime.h>
#include <hip/hip_bf16.h>
#include <math.h>

#define BATCH 2048
#define INDIM 512
#define HID   256
#define NRIM  16
#define VAL   400
#define ONUM  8
#define CH    4
#define CK    32
#define CV    256
#define KACT  8
#define K2P   704   // GRU K padded to multiple of 64 (672 -> 704)

typedef __hip_bfloat16 hbf;
typedef __attribute__((ext_vector_type(8))) __bf16 bf16x8;
typedef __attribute__((ext_vector_type(4))) float f32x4;

__device__ __forceinline__ float sigmoidf_(float x) { return 1.0f / (1.0f + expf(-x)); }

#define GLL(g, l) __builtin_amdgcn_global_load_lds(                                   \
    (const __attribute__((address_space(1))) void*)(g),                               \
    (__attribute__((address_space(3))) void*)(l), 16, 0, 0)

// ---------------- K1s: scores, top-k mask, softmax p0 (16 batches / block) ---------
__global__ __launch_bounds__(256)
void k1s(const float* __restrict__ option, const float* __restrict__ p_w,
         const float* __restrict__ p_b, float* __restrict__ p0g, float* __restrict__ maskg)
{
    const int t  = threadIdx.x;
    const int bb = t >> 4, n = t & 15;
    const int b  = blockIdx.x * 16 + bb;
    __shared__ float sc[16][17];

    float s0 = p_b[n], s1 = 0.0f;
    #pragma unroll
    for (int o = 0; o < ONUM; ++o) {
        s0 = fmaf(option[(b * 2 + 0) * ONUM + o], p_w[o * NRIM + n], s0);
        s1 = fmaf(option[(b * 2 + 1) * ONUM + o], p_w[o * NRIM + n], s1);
    }
    sc[bb][n] = s0;
    __syncthreads();

    int rank = 0;
    #pragma unroll
    for (int m = 0; m < NRIM; ++m) {
        float sm = sc[bb][m];
        if (sm > s0 || (sm == s0 && m < n)) rank++;
    }
    float mk = (rank < KACT) ? 1.0f : 0.0f;
    float mx = fmaxf(s0, s1);
    float e0 = expf(s0 - mx), e1 = expf(s1 - mx);
    p0g[b * NRIM + n]   = e0 / (e0 + e1);
    maskg[b * NRIM + n] = mk;
}

// ---------------- x -> bf16 --------------------------------------------------------
__global__ __launch_bounds__(256)
void k_xb(const float* __restrict__ x, hbf* __restrict__ xB)
{
    const int i = blockIdx.x * 256 + threadIdx.x;   // 1M/4 elems
    float4 v = ((const float4*)x)[i];
    hbf o[4] = { __float2bfloat16(v.x), __float2bfloat16(v.y),
                 __float2bfloat16(v.z), __float2bfloat16(v.w) };
    *(ulong1*)(xB + (size_t)i * 4) = *(ulong1*)o;
}

// ---------------- K1b: A2[b][n][K2P] = [ bf16(hs) | masked inputs | 0 pad ] --------
__global__ __launch_bounds__(256)
void k1b_a2(const float* __restrict__ hs, const float* __restrict__ vl0,
            const float* __restrict__ p0g, const float* __restrict__ maskg,
            const float* __restrict__ value_b, hbf* __restrict__ A2)
{
    const int b = blockIdx.x;
    const int t = threadIdx.x;
    __shared__ float vS[VAL];
    for (int j = t; j < VAL; j += 256) vS[j] = vl0[(size_t)b * 512 + j];
    __syncthreads();

    for (int n = 0; n < NRIM; ++n) {
        size_t ro = ((size_t)b * NRIM + n) * K2P;
        float p0 = p0g[b * NRIM + n], mk = maskg[b * NRIM + n];
        A2[ro + t] = __float2bfloat16(hs[((size_t)b * NRIM + n) * HID + t]);
        for (int j = t; j < VAL; j += 256)
            A2[ro + 256 + j] = __float2bfloat16(mk * (p0 * vS[j] + (1.0f - p0) * value_b[j]));
        if (t < 48) A2[ro + 656 + t] = __float2bfloat16(0.0f);
    }
}

// ---------------- zero fill (bf16, nelem8 = count of 16B chunks) -------------------
__global__ __launch_bounds__(256)
void k_zero(hbf* __restrict__ p, long nelem8)
{
    long i = (long)blockIdx.x * 256 + threadIdx.x;
    if (i < nelem8) {
        uint4 z; z.x = 0; z.y = 0; z.z = 0; z.w = 0;
        ((uint4*)p)[i] = z;
    }
}

// ---------------- transpose+convert: dst[n][coff+cmap(c)][koff+k] = src[n][k][c] ---
__global__ __launch_bounds__(256)
void t_conv(const float* __restrict__ src, hbf* __restrict__ dst,
            int K, int C, long s_nstride, long d_nstride, int dstride,
            int koff, int coff, int cmode)
{
    const int n  = blockIdx.z;
    const int c0 = blockIdx.x * 32, k0 = blockIdx.y * 32;
    const int tx = threadIdx.x & 31, ty = threadIdx.x >> 5;
    __shared__ float tile[32][33];
    const float* s = src + (size_t)n * s_nstride;
    #pragma unroll
    for (int i = 0; i < 4; ++i) {
        int k = k0 + ty + i * 8, c = c0 + tx;
        tile[ty + i * 8][tx] = (k < K && c < C) ? s[(size_t)k * C + c] : 0.0f;
    }
    __syncthreads();
    hbf* d = dst + (size_t)n * d_nstride;
    #pragma unroll
    for (int i = 0; i < 4; ++i) {
        int c = c0 + ty + i * 8, k = k0 + tx;
        if (c < C && k < K) {
            int cc = coff + (cmode ? (c < 512 ? c : c + 256) : c);
            d[(size_t)cc * dstride + koff + k] = __float2bfloat16(tile[tx][ty + i * 8]);
        }
    }
}

// ------ MFMA GEMM core: BK=64, swizzled LDS (pre-swizzled global src, rule #21) ----
// C[128x128] += A[128xK] * B^T[128xK]; As/Bs = [128][64] shorts (16KB each).
__device__ __forceinline__ void gemm_core64(const hbf* __restrict__ A, long lda,
                                            const hbf* __restrict__ B, long ldb,
                                            int K, short* As, short* Bs, f32x4 acc[4][4])
{
    const int t = threadIdx.x;
    const int w = t >> 6, lane = t & 63;
    const int l15 = lane & 15, l4 = lane >> 4;
    const int rl = lane >> 3;                 // row within this wave's 8-row group
    const int gu = (lane & 7) ^ rl;           // pre-swizzled source 16B-unit
    const int l7 = l15 & 7;

    for (int kk = 0; kk < K; kk += 64) {
        __syncthreads();
        #pragma unroll
        for (int q = 0; q < 4; ++q) {
            int row = q * 32 + w * 8 + rl;
            GLL(A + (size_t)row * lda + kk + gu * 8, As + (q * 32 + w * 8) * 64);
            GLL(B + (size_t)row * ldb + kk + gu * 8, Bs + (q * 32 + w * 8) * 64);
        }
        __syncthreads();

        const int wr = w >> 1, wc = w & 1;
        #pragma unroll
        for (int ks = 0; ks < 2; ++ks) {
            const int p = (ks * 4 + l4) ^ l7;  // swizzled read unit
            bf16x8 af[4], bfr[4];
            #pragma unroll
            for (int m = 0; m < 4; ++m)
                af[m] = *(const bf16x8*)(As + (wr * 64 + m * 16 + l15) * 64 + p * 8);
            #pragma unroll
            for (int nb = 0; nb < 4; ++nb)
                bfr[nb] = *(const bf16x8*)(Bs + (wc * 64 + nb * 16 + l15) * 64 + p * 8);
            #pragma unroll
            for (int m = 0; m < 4; ++m)
                #pragma unroll
                for (int nb = 0; nb < 4; ++nb)
                    acc[m][nb] = __builtin_amdgcn_mfma_f32_16x16x32_bf16(af[m], bfr[nb], acc[m][nb], 0, 0, 0);
        }
    }
}

// ---------------- K1v GEMM: vl0[2048][512] = xB @ Wv^T + value_b -------------------
__global__ __launch_bounds__(256)
void k1v(const hbf* __restrict__ xB, const hbf* __restrict__ Wv,
         const float* __restrict__ value_b, float* __restrict__ vl0)
{
    __shared__ __align__(16) short As[128 * 64];
    __shared__ __align__(16) short Bs[128 * 64];
    const int m0 = (blockIdx.x >> 2) * 128;
    const int c0 = (blockIdx.x & 3) * 128;

    const hbf* A = xB + (size_t)m0 * INDIM;
    const hbf* B = Wv + (size_t)c0 * INDIM;

    f32x4 acc[4][4];
    f32x4 zz = {0.0f, 0.0f, 0.0f, 0.0f};
    #pragma unroll
    for (int m = 0; m < 4; ++m)
        #pragma unroll
        for (int nb = 0; nb < 4; ++nb) acc[m][nb] = zz;

    gemm_core64(A, INDIM, B, INDIM, INDIM, As, Bs, acc);

    const int t = threadIdx.x;
    const int w = t >> 6, lane = t & 63, l15 = lane & 15, l4 = lane >> 4;
    const int wr = w >> 1, wc = w & 1;
    #pragma unroll
    for (int nb = 0; nb < 4; ++nb) {
        int col = c0 + wc * 64 + nb * 16 + l15;
        float bias = (col < VAL) ? value_b[col] : 0.0f;
        #pragma unroll
        for (int m = 0; m < 4; ++m)
            #pragma unroll
            for (int j = 0; j < 4; ++j) {
                int row = m0 + wr * 64 + m * 16 + l4 * 4 + j;
                vl0[(size_t)row * 512 + col] = acc[m][nb][j] + bias;
            }
    }
}

// ---------------- K2 GEMM: g[b][n][1024] = A2[b][n][:] @ W2[n][c][:]^T -------------
__global__ __launch_bounds__(256)
void k2g(const hbf* __restrict__ A2, const hbf* __restrict__ W2, hbf* __restrict__ g)
{
    __shared__ __align__(16) short As[128 * 64];
    __shared__ __align__(16) short Bs[128 * 64];
    const int id = blockIdx.x;
    const int xcd = id & 7, idx = id >> 3;
    const int n  = xcd + ((idx >> 7) << 3);
    const int rem = idx & 127;
    const int m0 = (rem >> 3) * 128;
    const int c0 = (rem & 7) * 128;

    const hbf* A = A2 + (size_t)n * K2P + (size_t)m0 * (NRIM * K2P);
    const hbf* B = W2 + (size_t)n * (1024 * K2P) + (size_t)c0 * K2P;

    f32x4 acc[4][4];
    f32x4 zz = {0.0f, 0.0f, 0.0f, 0.0f};
    #pragma unroll
    for (int m = 0; m < 4; ++m)
        #pragma unroll
        for (int nb = 0; nb < 4; ++nb) acc[m][nb] = zz;

    gemm_core64(A, NRIM * K2P, B, K2P, K2P, As, Bs, acc);

    const int t = threadIdx.x;
    const int w = t >> 6, lane = t & 63, l15 = lane & 15, l4 = lane >> 4;
    const int wr = w >> 1, wc = w & 1;
    #pragma unroll
    for (int m = 0; m < 4; ++m)
        #pragma unroll
        for (int nb = 0; nb < 4; ++nb) {
            int col = c0 + wc * 64 + nb * 16 + l15;
            #pragma unroll
            for (int j = 0; j < 4; ++j) {
                int row = m0 + wr * 64 + m * 16 + l4 * 4 + j;
                g[((size_t)row * NRIM + n) * 1024 + col] = __float2bfloat16(acc[m][nb][j]);
            }
        }
}

// ---------------- GRU elementwise epilogue -----------------------------------------
__global__ __launch_bounds__(256)
void k_gru_ep(const hbf* __restrict__ g, const float* __restrict__ hs, hbf* __restrict__ hyB)
{
    const size_t row = blockIdx.x;
    const int t = threadIdx.x;
    const hbf* gr = g + row * 1024;
    float r  = __bfloat162float(gr[t]);
    float ig = __bfloat162float(gr[t + 256]);
    float xn = __bfloat162float(gr[t + 512]);
    float hn = __bfloat162float(gr[t + 768]);
    float reset = sigmoidf_(r);
    float inp   = sigmoidf_(ig);
    float newg  = tanhf(xn + reset * hn);
    float h     = hs[row * HID + t];
    hyB[row * HID + t] = __float2bfloat16(newg + inp * (h - newg));
}

// ---------------- K3 GEMM: qkv[b][n][1280] = hy @ Wqkv^T ---------------------------
__global__ __launch_bounds__(256)
void k3g(const hbf* __restrict__ hyB, const hbf* __restrict__ Wqkv, hbf* __restrict__ qkv)
{
    __shared__ __align__(16) short As[128 * 64];
    __shared__ __align__(16) short Bs[128 * 64];
    const int id = blockIdx.x;
    const int xcd = id & 7, idx = id >> 3;          // idx in [0,320)
    const int n  = xcd + (idx / 160) * 8;
    const int rem = idx % 160;
    const int m0 = (rem / 10) * 128;
    const int c0 = (rem % 10) * 128;

    const hbf* A = hyB + (size_t)n * HID + (size_t)m0 * (NRIM * HID);
    const hbf* B = Wqkv + (size_t)n * (1280 * 256) + (size_t)c0 * 256;

    f32x4 acc[4][4];
    f32x4 zz = {0.0f, 0.0f, 0.0f, 0.0f};
    #pragma unroll
    for (int m = 0; m < 4; ++m)
        #pragma unroll
        for (int nb = 0; nb < 4; ++nb) acc[m][nb] = zz;

    gemm_core64(A, NRIM * HID, B, 256, 256, As, Bs, acc);

    const int t = threadIdx.x;
    const int w = t >> 6, lane = t & 63, l15 = lane & 15, l4 = lane >> 4;
    const int wr = w >> 1, wc = w & 1;
    #pragma unroll
    for (int m = 0; m < 4; ++m)
        #pragma unroll
        for (int nb = 0; nb < 4; ++nb) {
            int col = c0 + wc * 64 + nb * 16 + l15;
            #pragma unroll
            for (int j = 0; j < 4; ++j) {
                int row = m0 + wr * 64 + m * 16 + l4 * 4 + j;
                qkv[((size_t)row * NRIM + n) * 1280 + col] = __float2bfloat16(acc[m][nb][j]);
            }
        }
}

// ---------------- K4: attention per (h, b) -----------------------------------------
__global__ __launch_bounds__(256)
void k4_attn(const hbf* __restrict__ qkv, const float* __restrict__ maskg,
             hbf* __restrict__ ctx)
{
    const int h = blockIdx.x;
    const int b = blockIdx.y;
    const int t = threadIdx.x;

    __shared__ float qS[NRIM][33], kS[NRIM][33];
    __shared__ float sS[NRIM][17];
    __shared__ float vS[NRIM][CV];
    __shared__ float mS[NRIM];

    for (int idx = t; idx < NRIM * CK; idx += 256) {
        int n2 = idx >> 5, i = idx & 31;
        size_t base = ((size_t)b * NRIM + n2) * 1280;
        qS[n2][i] = __bfloat162float(qkv[base + h * CK + i]);
        kS[n2][i] = __bfloat162float(qkv[base + 128 + h * CK + i]);
    }
    for (int idx = t; idx < NRIM * CV; idx += 256) {
        int m2 = idx >> 8, c = idx & 255;
        vS[m2][c] = __bfloat162float(qkv[((size_t)b * NRIM + m2) * 1280 + 256 + h * CV + c]);
    }
    if (t < NRIM) mS[t] = maskg[b * NRIM + t];
    __syncthreads();

    {
        int nn = t >> 4, mm = t & 15;
        float s = 0.f;
        #pragma unroll
        for (int i = 0; i < CK; ++i) s = fmaf(qS[nn][i], kS[mm][i], s);
        sS[nn][mm] = s * 0.17677669529663687f;
    }
    __syncthreads();

    if (t < NRIM) {
        float mx = -1e30f;
        #pragma unroll
        for (int m2 = 0; m2 < NRIM; ++m2) mx = fmaxf(mx, sS[t][m2]);
        float sum = 0.f;
        #pragma unroll
        for (int m2 = 0; m2 < NRIM; ++m2) { float e = expf(sS[t][m2] - mx); sS[t][m2] = e; sum += e; }
        float inv = mS[t] / sum;
        #pragma unroll
        for (int m2 = 0; m2 < NRIM; ++m2) sS[t][m2] *= inv;
    }
    __syncthreads();

    for (int n2 = 0; n2 < NRIM; ++n2) {
        float acc = 0.f;
        #pragma unroll
        for (int m2 = 0; m2 < NRIM; ++m2) acc = fmaf(sS[n2][m2], vS[m2][t], acc);
        ctx[((size_t)b * NRIM + n2) * 1024 + h * CV + t] = __float2bfloat16(acc);
    }
}

// ---------------- K5 GEMM: out = mask ? ctx @ Wout^T + hy : hs ---------------------
__global__ __launch_bounds__(256)
void k5g(const hbf* __restrict__ ctx, const hbf* __restrict__ Wout,
         const hbf* __restrict__ hyB, const float* __restrict__ hs,
         const float* __restrict__ maskg, float* __restrict__ out)
{
    __shared__ __align__(16) short As[128 * 64];
    __shared__ __align__(16) short Bs[128 * 64];
    const int id = blockIdx.x;
    const int xcd = id & 7, idx = id >> 3;          // idx in [0,64)
    const int n  = xcd + ((idx >> 5) << 3);
    const int rem = idx & 31;
    const int m0 = (rem >> 1) * 128;
    const int c0 = (rem & 1) * 128;

    const hbf* A = ctx + (size_t)n * 1024 + (size_t)m0 * (NRIM * 1024);
    const hbf* B = Wout + (size_t)n * (256 * 1024) + (size_t)c0 * 1024;

    f32x4 acc[4][4];
    f32x4 zz = {0.0f, 0.0f, 0.0f, 0.0f};
    #pragma unroll
    for (int m = 0; m < 4; ++m)
        #pragma unroll
        for (int nb = 0; nb < 4; ++nb) acc[m][nb] = zz;

    gemm_core64(A, NRIM * 1024, B, 1024, 1024, As, Bs, acc);

    const int t = threadIdx.x;
    const int w = t >> 6, lane = t & 63, l15 = lane & 15, l4 = lane >> 4;
    const int wr = w >> 1, wc = w & 1;
    #pragma unroll
    for (int m = 0; m < 4; ++m)
        #pragma unroll
        for (int nb = 0; nb < 4; ++nb) {
            int col = c0 + wc * 64 + nb * 16 + l15;
            #pragma unroll
            for (int j = 0; j < 4; ++j) {
                int row = m0 + wr * 64 + m * 16 + l4 * 4 + j;
                size_t idx2 = ((size_t)row * NRIM + n) * HID + col;
                float mk = maskg[row * NRIM + n];
                out[idx2] = (mk > 0.5f) ? (acc[m][nb][j] + __bfloat162float(hyB[idx2]))
                                        : hs[idx2];
            }
        }
}

extern "C" void kernel_launch(void* const* d_in, const int* in_sizes, int n_in,
                              void* d_out, int out_size, void* d_ws, size_t ws_size,
                              hipStream_t stream) {
    const float* x       = (const float*)d_in[0];
    const float* hs      = (const float*)d_in[1];
    const float* option  = (const float*)d_in[2];
    const float* value_w = (const float*)d_in[3];
    const float* value_b = (const float*)d_in[4];
    const float* p_w     = (const float*)d_in[5];
    const float* p_b     = (const float*)d_in[6];
    const float* x2h_w   = (const float*)d_in[7];
    const float* h2h_w   = (const float*)d_in[8];
    const float* q_w     = (const float*)d_in[9];
    const float* k_w     = (const float*)d_in[10];
    const float* v_w     = (const float*)d_in[11];
    const float* out_w   = (const float*)d_in[12];
    float* out = (float*)d_out;

    char* ws = (char*)d_ws;
    // region0: A2 (46.1 MB, [2048][16][704]) / ctx (67 MB) union
    hbf* A2   = (hbf*)(ws);
    hbf* ctx  = (hbf*)(ws);
    size_t off = 67108864;
    // region1: g (67 MB) / qkv (84 MB) union
    hbf* g    = (hbf*)(ws + off);
    hbf* qkv  = (hbf*)(ws + off);
    off += 83886080;
    hbf* W2   = (hbf*)(ws + off); off += 23068672;   // [16][1024][704]
    hbf* Wqkv = (hbf*)(ws + off); off += 10485760;   // [16][1280][256]
    hbf* Wout = (hbf*)(ws + off); off += 8388608;    // [16][256][1024]
    hbf* hyB  = (hbf*)(ws + off); off += 16777216;   // [32768][256]
    float* vl0   = (float*)(ws + off); off += 4194304;   // [2048][512] f32
    hbf* xB   = (hbf*)(ws + off); off += 2097152;    // [2048][512] bf16
    hbf* Wv   = (hbf*)(ws + off); off += 524288;     // [512][512] bf16
    float* p0g   = (float*)(ws + off); off += 131072;
    float* maskg = (float*)(ws + off); off += 131072;

    // --- weight conversion (transpose to [cols][K], bf16) ---
    k_zero<<<dim3(5632), dim3(256), 0, stream>>>(W2, 1441792L);
    k_zero<<<dim3(128), dim3(256), 0, stream>>>(Wv, 32768L);
    t_conv<<<dim3(24, 8, 16), dim3(256), 0, stream>>>(h2h_w, W2, 256, 768,
            196608L, 720896L, K2P, 0, 0, 1);
    t_conv<<<dim3(24, 13, 16), dim3(256), 0, stream>>>(x2h_w, W2, 400, 768,
            307200L, 720896L, K2P, 256, 0, 0);
    t_conv<<<dim3(4, 8, 16), dim3(256), 0, stream>>>(q_w, Wqkv, 256, 128,
            32768L, 327680L, 256, 0, 0, 0);
    t_conv<<<dim3(4, 8, 16), dim3(256), 0, stream>>>(k_w, Wqkv, 256, 128,
            32768L, 327680L, 256, 0, 128, 0);
    t_conv<<<dim3(32, 8, 16), dim3(256), 0, stream>>>(v_w, Wqkv, 256, 1024,
            262144L, 327680L, 256, 0, 256, 0);
    t_conv<<<dim3(8, 32, 16), dim3(256), 0, stream>>>(out_w, Wout, 1024, 256,
            262144L, 262144L, 1024, 0, 0, 0);
    t_conv<<<dim3(13, 16, 1), dim3(256), 0, stream>>>(value_w, Wv, 512, 400,
            0L, 0L, 512, 0, 0, 0);

    // --- gating + value GEMM + inputs ---
    k1s<<<dim3(BATCH / 16), dim3(256), 0, stream>>>(option, p_w, p_b, p0g, maskg);
    k_xb<<<dim3(1024), dim3(256), 0, stream>>>(x, xB);
    k1v<<<dim3(64), dim3(256), 0, stream>>>(xB, Wv, value_b, vl0);
    k1b_a2<<<dim3(BATCH), dim3(256), 0, stream>>>(hs, vl0, p0g, maskg, value_b, A2);

    // --- GRU gates GEMM + elementwise ---
    k2g<<<dim3(2048), dim3(256), 0, stream>>>(A2, W2, g);
    k_gru_ep<<<dim3(BATCH * NRIM), dim3(256), 0, stream>>>(g, hs, hyB);

    // --- QKV GEMM ---
    k3g<<<dim3(2560), dim3(256), 0, stream>>>(hyB, Wqkv, qkv);

    // --- attention ---
    k4_attn<<<dim3(CH, BATCH), dim3(256), 0, stream>>>(qkv, maskg, ctx);

    // --- output projection GEMM (fused mask/residual) ---
    k5g<<<dim3(512), dim3(256), 0, stream>>>(ctx, Wout, hyB, hs, maskg, out);
}